// Round 8
// baseline (69.847 us; speedup 1.0000x reference)
//
#include <hip/hip_runtime.h>
#include <hip/hip_fp16.h>

typedef _Float16 half8 __attribute__((ext_vector_type(8)));
typedef _Float16 half2v __attribute__((ext_vector_type(2)));
typedef float f32x16 __attribute__((ext_vector_type(16)));

#define BM 128
#define BN 128
#define BK 64
#define THREADS 256
#define LDS_A (BM * BK * 2)        // 16 KB
#define LDS_B (BN * BK * 2)        // 16 KB  (total 32 KB, single buffer)

__device__ inline unsigned pkrtz(float lo, float hi) {
  return __builtin_bit_cast(unsigned, __builtin_amdgcn_cvt_pkrtz(lo, hi));
}

// raw barrier: lgkm drain only — global prefetch loads stay in flight
#define BAR() do { \
  asm volatile("s_waitcnt lgkmcnt(0)" ::: "memory"); \
  __builtin_amdgcn_s_barrier(); \
} while (0)

__global__ void init_out_kernel(const float* __restrict__ bias,
                                float* __restrict__ out, int MN, int N) {
  int i = (blockIdx.x * blockDim.x + threadIdx.x) * 4;
  if (i < MN) *(float4*)(out + i) = *(const float4*)(bias + (i % N));
}

__global__ void reduce_kernel(const float* __restrict__ ws,
                              const float* __restrict__ bias,
                              float* __restrict__ out, int MN, int N, int S) {
  int i = (blockIdx.x * blockDim.x + threadIdx.x) * 4;
  if (i >= MN) return;
  float4 a = *(const float4*)(bias + (i % N));
  for (int z = 0; z < S; ++z) {
    float4 p = *(const float4*)(ws + (size_t)z * MN + i);
    a.x += p.x; a.y += p.y; a.z += p.z; a.w += p.w;
  }
  *(float4*)(out + i) = a;
}

struct Pf {
  float4 a[8];              // 32 fp32 of x (half a row's K-tile)
  int w0, w1, w2, w3;       // 4 packed qweight words (32 k)
  int zv;                   // zero nibble
  float s;                  // scale
};

__global__ __launch_bounds__(THREADS, 4) void qgemm_kernel(
    const float* __restrict__ x, const int* __restrict__ qw,
    const int* __restrict__ qz, const float* __restrict__ sc,
    float* __restrict__ target, int N, int K, int S, int use_ws) {
  __shared__ __align__(16) unsigned char smem[LDS_A + LDS_B];  // 32 KB
  const int tid = threadIdx.x;
  const int n0 = blockIdx.x * BN;
  const int z = blockIdx.z;
  const int KC = K / S;              // 512 at S=8
  const int kbase = z * KC;
  const int nt = KC / BK;            // 8
  const int lane = tid & 63;
  const int wid = tid >> 6;          // 0..3
  const int wr = wid >> 1;           // 0..1 (M, 64 rows each)
  const int wc = wid & 1;            // 0..1 (N, 64 cols each)
  const int l31 = lane & 31;
  const int l5 = lane >> 5;
  const int N8 = N >> 3;

  f32x16 acc[2][2] = {};

  // A staging: 2 threads/row; arow 0..127, half ah -> 32 k = units au0..au0+3
  const int arow = tid >> 1;
  const int ah = tid & 1;
  const int au0 = ah * 4;
  // B staging: col = tid&127, 4 packed words = units brow4..brow4+3
  const int bcol = tid & 127;
  const int brow4 = (tid >> 7) * 4;  // 0 or 4
  const int gn = n0 + bcol;

  auto LOAD = [&](int t, Pf& p) {
    int k0 = kbase + t * BK;
    const float* src = x + arow * K + k0 + ah * 32;
#pragma unroll
    for (int j = 0; j < 8; ++j) p.a[j] = *(const float4*)(src + 4 * j);
    int g = k0 >> 7;
    int kq0 = (k0 >> 3) + brow4;
    p.w0 = qw[(kq0 + 0) * N + gn];
    p.w1 = qw[(kq0 + 1) * N + gn];
    p.w2 = qw[(kq0 + 2) * N + gn];
    p.w3 = qw[(kq0 + 3) * N + gn];
    p.zv = (qz[g * N8 + (gn >> 3)] >> ((bcol & 7) * 4)) & 0xF;
    p.s = sc[g * N + gn];
  };

  // k-order inside each 16B unit (A and B identical): [0,4,1,5,2,6,3,7]
  auto STORE = [&](const Pf& p) {
    // A: 32 fp32 -> 4 units; unit j from floats [8j..8j+7], pairs (k,k+4)
#pragma unroll
    for (int j = 0; j < 4; ++j) {
      uint4 q;
      q.x = pkrtz(p.a[2 * j].x, p.a[2 * j + 1].x);
      q.y = pkrtz(p.a[2 * j].y, p.a[2 * j + 1].y);
      q.z = pkrtz(p.a[2 * j].z, p.a[2 * j + 1].z);
      q.w = pkrtz(p.a[2 * j].w, p.a[2 * j + 1].w);
      int u = au0 + j;
      *(uint4*)(smem + arow * 128 + ((u ^ (arow & 7)) << 4)) = q;
    }
    // B: dequant 4 words -> 4 units
    unsigned char* bb = smem + LDS_A;
    unsigned zrep = (0x6400u + (unsigned)p.zv + 1u) * 0x00010001u;
    half2v zh = __builtin_bit_cast(half2v, zrep);
    unsigned srep = pkrtz(p.s, p.s);
    half2v sh = __builtin_bit_cast(half2v, srep);
    const unsigned vw[4] = {(unsigned)p.w0, (unsigned)p.w1,
                            (unsigned)p.w2, (unsigned)p.w3};
#pragma unroll
    for (int j = 0; j < 4; ++j) {
      uint4 q;
#pragma unroll
      for (int b = 0; b < 4; ++b) {
        unsigned tt = ((vw[j] >> (4 * b)) & 0x000F000Fu) | 0x64006400u;
        half2v h = (__builtin_bit_cast(half2v, tt) - zh) * sh;
        (&q.x)[b] = __builtin_bit_cast(unsigned, h);
      }
      int u = brow4 + j;
      *(uint4*)(bb + bcol * 128 + ((u ^ (bcol & 7)) << 4)) = q;
    }
  };

  auto COMPUTE = [&]() {
    unsigned char* bb = smem + LDS_A;
#pragma unroll
    for (int kk = 0; kk < 4; ++kk) {
      half8 a[2], b[2];
      int u = kk * 2 + l5;           // this lane-half's 8-k window
#pragma unroll
      for (int fi = 0; fi < 2; ++fi) {
        int row = wr * 64 + fi * 32 + l31;
        a[fi] = *(half8*)(smem + row * 128 + ((u ^ (row & 7)) << 4));
      }
#pragma unroll
      for (int fj = 0; fj < 2; ++fj) {
        int col = wc * 64 + fj * 32 + l31;
        b[fj] = *(half8*)(bb + col * 128 + ((u ^ (col & 7)) << 4));
      }
#pragma unroll
      for (int fi = 0; fi < 2; ++fi)
#pragma unroll
        for (int fj = 0; fj < 2; ++fj)
          acc[fi][fj] = __builtin_amdgcn_mfma_f32_32x32x16_f16(
              a[fi], b[fj], acc[fi][fj], 0, 0, 0);
    }
  };

  // single-buffer 2-barrier loop; next tile's loads in flight across COMPUTE
  Pf p;
  LOAD(0, p);
  for (int t = 0; t < nt; ++t) {
    BAR();                       // previous COMPUTE done reading LDS
    STORE(p);                    // reg -> LDS (waits vmcnt internally)
    if (t + 1 < nt) LOAD(t + 1, p);   // issue next tile's global loads
    BAR();                       // ds_writes visible to all waves
    COMPUTE();
  }

  // epilogue: C/D (32x32): col=lane&31, row=(r&3)+8*(r>>2)+4*(lane>>5)
  if (use_ws) {
    float* o = target + (size_t)z * (size_t)BM * N;
#pragma unroll
    for (int fi = 0; fi < 2; ++fi)
#pragma unroll
      for (int fj = 0; fj < 2; ++fj) {
        int gc = n0 + wc * 64 + fj * 32 + l31;
#pragma unroll
        for (int r = 0; r < 16; ++r) {
          int gm = wr * 64 + fi * 32 + (r & 3) + 8 * (r >> 2) + 4 * l5;
          o[(size_t)gm * N + gc] = acc[fi][fj][r];
        }
      }
  } else {
#pragma unroll
    for (int fi = 0; fi < 2; ++fi)
#pragma unroll
      for (int fj = 0; fj < 2; ++fj) {
        int gc = n0 + wc * 64 + fj * 32 + l31;
#pragma unroll
        for (int r = 0; r < 16; ++r) {
          int gm = wr * 64 + fi * 32 + (r & 3) + 8 * (r >> 2) + 4 * l5;
          unsafeAtomicAdd(&target[(size_t)gm * N + gc], acc[fi][fj][r]);
        }
      }
  }
}

extern "C" void kernel_launch(void* const* d_in, const int* in_sizes, int n_in,
                              void* d_out, int out_size, void* d_ws, size_t ws_size,
                              hipStream_t stream) {
  const float* x = (const float*)d_in[0];
  const int* qw = (const int*)d_in[1];
  const int* qz = (const int*)d_in[2];
  const float* sc = (const float*)d_in[3];
  const float* bias = (const float*)d_in[4];
  float* out = (float*)d_out;

  int N = in_sizes[4];
  int K = (in_sizes[1] / N) * 8;
  int M = in_sizes[0] / K;           // == BM == 128
  int MN = M * N;
  size_t slice = (size_t)MN * 4;

  int S = 0;
  if (ws_size >= 8 * slice) S = 8;
  else if (ws_size >= 4 * slice) S = 4;
  else if (ws_size >= 2 * slice) S = 2;

  if (S > 0) {
    dim3 grid(N / BN, 1, S);
    qgemm_kernel<<<grid, THREADS, 0, stream>>>(x, qw, qz, sc, (float*)d_ws,
                                               N, K, S, 1);
    reduce_kernel<<<(MN / 4 + 255) / 256, 256, 0, stream>>>(
        (const float*)d_ws, bias, out, MN, N, S);
  } else {
    init_out_kernel<<<(MN / 4 + 255) / 256, 256, 0, stream>>>(bias, out, MN, N);
    dim3 grid(N / BN, 1, 8);
    qgemm_kernel<<<grid, THREADS, 0, stream>>>(x, qw, qz, sc, out, N, K, 8, 0);
  }
}

// Round 9
// 48.684 us; speedup vs baseline: 1.4347x; 1.4347x over previous
//
#include <hip/hip_runtime.h>
#include <hip/hip_fp16.h>

typedef _Float16 half8 __attribute__((ext_vector_type(8)));
typedef _Float16 half2v __attribute__((ext_vector_type(2)));
typedef float f32x16 __attribute__((ext_vector_type(16)));

#define BM 128
#define BN 256
#define BK 64
#define THREADS 512
#define LDS_TILE (BM * BK * 2)   // 16 KB per buffer, 32 KB total

__device__ inline unsigned pkrtz(float lo, float hi) {
  return __builtin_bit_cast(unsigned, __builtin_amdgcn_cvt_pkrtz(lo, hi));
}

// raw barrier: lgkm drain only — all global loads stay in flight
#define BAR() do { \
  asm volatile("s_waitcnt lgkmcnt(0)" ::: "memory"); \
  __builtin_amdgcn_s_barrier(); \
} while (0)

__global__ void init_out_kernel(const float* __restrict__ bias,
                                float* __restrict__ out, int MN, int N) {
  int i = (blockIdx.x * blockDim.x + threadIdx.x) * 4;
  if (i < MN) *(float4*)(out + i) = *(const float4*)(bias + (i % N));
}

__global__ void reduce_kernel(const float* __restrict__ ws,
                              const float* __restrict__ bias,
                              float* __restrict__ out, int MN, int N, int S) {
  int i = (blockIdx.x * blockDim.x + threadIdx.x) * 4;
  if (i >= MN) return;
  float4 a = *(const float4*)(bias + (i % N));
  for (int z = 0; z < S; ++z) {
    float4 p = *(const float4*)(ws + (size_t)z * MN + i);
    a.x += p.x; a.y += p.y; a.z += p.z; a.w += p.w;
  }
  *(float4*)(out + i) = a;
}

// per-phase B-stream registers: 4 qw words per col-frag + dequant constants
struct Bs {
  unsigned w0[4], w1[4];
  unsigned zr0, sr0, zr1, sr1;
};

__device__ inline half8 dequant(unsigned w, unsigned zr, unsigned sr) {
  half2v zh = __builtin_bit_cast(half2v, zr);
  half2v sh = __builtin_bit_cast(half2v, sr);
  unsigned u0 = (w & 0x000F000Fu) | 0x64006400u;          // k-pair (0,4)
  unsigned u1 = ((w >> 4) & 0x000F000Fu) | 0x64006400u;   // (1,5)
  unsigned u2 = ((w >> 8) & 0x000F000Fu) | 0x64006400u;   // (2,6)
  unsigned u3 = ((w >> 12) & 0x000F000Fu) | 0x64006400u;  // (3,7)
  uint4 r;
  r.x = __builtin_bit_cast(unsigned, (half2v)((__builtin_bit_cast(half2v, u0) - zh) * sh));
  r.y = __builtin_bit_cast(unsigned, (half2v)((__builtin_bit_cast(half2v, u1) - zh) * sh));
  r.z = __builtin_bit_cast(unsigned, (half2v)((__builtin_bit_cast(half2v, u2) - zh) * sh));
  r.w = __builtin_bit_cast(unsigned, (half2v)((__builtin_bit_cast(half2v, u3) - zh) * sh));
  return __builtin_bit_cast(half8, r);
}

__global__ __launch_bounds__(THREADS) void qgemm_kernel(
    const float* __restrict__ x, const int* __restrict__ qw,
    const int* __restrict__ qz, const float* __restrict__ sc,
    float* __restrict__ target, int N, int K, int S, int use_ws) {
  __shared__ __align__(16) unsigned char smem[2 * LDS_TILE];  // 32 KB
  const int tid = threadIdx.x;
  const int n0 = blockIdx.x * BN;
  const int z = blockIdx.z;
  const int KC = K / S;              // 512 at S=8
  const int kbase = z * KC;
  const int nt = KC / BK;            // 8 (even)
  const int lane = tid & 63;
  const int wid = tid >> 6;          // 0..7
  const int wr = wid >> 2;           // 0..1 (M-half, 64 rows)
  const int wc = wid & 3;            // 0..3 (N-quarter, 64 cols)
  const int l31 = lane & 31;
  const int l5 = lane >> 5;
  const int N8 = N >> 3;
  const int kqb = kbase >> 3;        // packed-row base

  f32x16 acc[2][2] = {};

  // A staging: 4 threads/row; arow 0..127, quarter aq -> 16 floats (2 units)
  const int arow = tid >> 2;
  const int aq = tid & 3;
  // B stream columns for this wave's two col-frags
  const int c0 = n0 + wc * 64 + l31;
  const int c1 = c0 + 32;

  float4 areg[4];
  auto LOADA = [&](int t) {
    const float* src = x + arow * K + kbase + t * BK + aq * 16;
#pragma unroll
    for (int j = 0; j < 4; ++j) areg[j] = *(const float4*)(src + 4 * j);
  };

  // unit u holds k [8u,8u+8) as pairs (k+i, k+i+4); swizzle u ^= row&7
  auto STOREA = [&](int buf) {
    unsigned char* base = smem + buf * LDS_TILE;
#pragma unroll
    for (int j = 0; j < 2; ++j) {
      uint4 q;
      q.x = pkrtz(areg[2 * j].x, areg[2 * j + 1].x);
      q.y = pkrtz(areg[2 * j].y, areg[2 * j + 1].y);
      q.z = pkrtz(areg[2 * j].z, areg[2 * j + 1].z);
      q.w = pkrtz(areg[2 * j].w, areg[2 * j + 1].w);
      int u = aq * 2 + j;
      *(uint4*)(base + arow * 128 + ((u ^ (arow & 7)) << 4)) = q;
    }
  };

  auto LOADB = [&](int t, Bs& b) {
    const int* q0 = qw + (kqb + t * 8 + l5) * N + c0;
#pragma unroll
    for (int s = 0; s < 4; ++s) {
      b.w0[s] = (unsigned)q0[2 * s * N];
      b.w1[s] = (unsigned)q0[2 * s * N + 32];
    }
    int g = (kbase + t * BK) >> 7;
    int zw0 = qz[g * N8 + (c0 >> 3)];
    int zw1 = qz[g * N8 + (c1 >> 3)];
    b.zr0 = (0x6401u + (unsigned)((zw0 >> ((c0 & 7) * 4)) & 0xF)) * 0x00010001u;
    b.zr1 = (0x6401u + (unsigned)((zw1 >> ((c1 & 7) * 4)) & 0xF)) * 0x00010001u;
    float s0 = sc[g * N + c0], s1 = sc[g * N + c1];
    b.sr0 = pkrtz(s0, s0);
    b.sr1 = pkrtz(s1, s1);
  };

  auto COMPUTE = [&](int buf, const Bs& b) {
    unsigned char* base = smem + buf * LDS_TILE;
#pragma unroll
    for (int s = 0; s < 4; ++s) {
      int u = 2 * s + l5;
      half8 a0, a1, b0, b1;
      {
        int row = wr * 64 + l31;
        a0 = *(half8*)(base + row * 128 + ((u ^ (row & 7)) << 4));
        row += 32;
        a1 = *(half8*)(base + row * 128 + ((u ^ (row & 7)) << 4));
      }
      b0 = dequant(b.w0[s], b.zr0, b.sr0);
      b1 = dequant(b.w1[s], b.zr1, b.sr1);
      acc[0][0] = __builtin_amdgcn_mfma_f32_32x32x16_f16(a0, b0, acc[0][0], 0, 0, 0);
      acc[0][1] = __builtin_amdgcn_mfma_f32_32x32x16_f16(a0, b1, acc[0][1], 0, 0, 0);
      acc[1][0] = __builtin_amdgcn_mfma_f32_32x32x16_f16(a1, b0, acc[1][0], 0, 0, 0);
      acc[1][1] = __builtin_amdgcn_mfma_f32_32x32x16_f16(a1, b1, acc[1][1], 0, 0, 0);
    }
  };

  // prologue
  Bs b0, b1;
  LOADA(0);
  LOADB(0, b0);
  STOREA(0);                 // tile 0 -> buf0
  LOADA(1);
  LOADB(1, b1);
  __syncthreads();

  // main loop: 2 phases/iter, 1 barrier/phase; B never touches LDS
  for (int t = 0; t < nt; t += 2) {
    // phase t (even): compute buf0 with b0
    STOREA(1);                               // tile t+1 (in areg) -> buf1
    { int tn = t + 2 < nt ? t + 2 : nt - 1; LOADA(tn); }
    COMPUTE(0, b0);
    { int tn = t + 2 < nt ? t + 2 : nt - 1; LOADB(tn, b0); }
    BAR();

    // phase t+1 (odd): compute buf1 with b1
    STOREA(0);                               // tile t+2 -> buf0
    { int tn = t + 3 < nt ? t + 3 : nt - 1; LOADA(tn); }
    COMPUTE(1, b1);
    { int tn = t + 3 < nt ? t + 3 : nt - 1; LOADB(tn, b1); }
    BAR();
  }

  // epilogue: C/D (32x32): col=lane&31, row=(r&3)+8*(r>>2)+4*(lane>>5)
  if (use_ws) {
    float* o = target + (size_t)z * (size_t)BM * N;
#pragma unroll
    for (int fi = 0; fi < 2; ++fi)
#pragma unroll
      for (int fj = 0; fj < 2; ++fj) {
        int gc = n0 + wc * 64 + fj * 32 + l31;
#pragma unroll
        for (int r = 0; r < 16; ++r) {
          int gm = wr * 64 + fi * 32 + (r & 3) + 8 * (r >> 2) + 4 * l5;
          o[(size_t)gm * N + gc] = acc[fi][fj][r];
        }
      }
  } else {
#pragma unroll
    for (int fi = 0; fi < 2; ++fi)
#pragma unroll
      for (int fj = 0; fj < 2; ++fj) {
        int gc = n0 + wc * 64 + fj * 32 + l31;
#pragma unroll
        for (int r = 0; r < 16; ++r) {
          int gm = wr * 64 + fi * 32 + (r & 3) + 8 * (r >> 2) + 4 * l5;
          unsafeAtomicAdd(&target[(size_t)gm * N + gc], acc[fi][fj][r]);
        }
      }
  }
}

extern "C" void kernel_launch(void* const* d_in, const int* in_sizes, int n_in,
                              void* d_out, int out_size, void* d_ws, size_t ws_size,
                              hipStream_t stream) {
  const float* x = (const float*)d_in[0];
  const int* qw = (const int*)d_in[1];
  const int* qz = (const int*)d_in[2];
  const float* sc = (const float*)d_in[3];
  const float* bias = (const float*)d_in[4];
  float* out = (float*)d_out;

  int N = in_sizes[4];
  int K = (in_sizes[1] / N) * 8;
  int M = in_sizes[0] / K;           // == BM == 128
  int MN = M * N;
  size_t slice = (size_t)MN * 4;

  int S = 0;
  if (ws_size >= 8 * slice) S = 8;
  else if (ws_size >= 4 * slice) S = 4;
  else if (ws_size >= 2 * slice) S = 2;

  if (S > 0) {
    dim3 grid(N / BN, 1, S);
    qgemm_kernel<<<grid, THREADS, 0, stream>>>(x, qw, qz, sc, (float*)d_ws,
                                               N, K, S, 1);
    reduce_kernel<<<(MN / 4 + 255) / 256, 256, 0, stream>>>(
        (const float*)d_ws, bias, out, MN, N, S);
  } else {
    init_out_kernel<<<(MN / 4 + 255) / 256, 256, 0, stream>>>(bias, out, MN, N);
    dim3 grid(N / BN, 1, 8);
    qgemm_kernel<<<grid, THREADS, 0, stream>>>(x, qw, qz, sc, out, N, K, 8, 0);
  }
}